// Round 3
// baseline (536.168 us; speedup 1.0000x reference)
//
#include <hip/hip_runtime.h>
#include <math.h>

typedef unsigned short u16;
typedef unsigned int u32;
typedef __attribute__((ext_vector_type(8))) short short8;   // 8 bf16 = 4 VGPRs
typedef __attribute__((ext_vector_type(4))) float float4v;  // MFMA accum

// ---------- constants ----------
#define BATCH   8192
#define OBS     21
#define HID     512
#define NL      10
#define OVERALL 5632            // HID*(NL+1)
#define IN_DIM  5653            // OBS + OVERALL
#define OUT_DIM 5640            // OVERALL + ACT
#define ACT     8

// output element offsets (flat concat, fp32 elements)
#define O_PM   0
#define O_LS   65536
#define O_NH   131072
#define O_NM   (131072 + BATCH*OVERALL)     // 46268416
#define O_NLS  (O_NM + 65536)               // 46333952

// packed workspace: 10 x 512 x 512 bf16 weight blocks (K-contiguous)
#define WSP_TOTAL (10*512*512)
#define WSP_BYTES ((size_t)WSP_TOTAL * 2)

__device__ __forceinline__ u16 f2bf(float f) {
    u32 u = __float_as_uint(f);
    u32 r = (u + 0x7fffu + ((u >> 16) & 1u)) >> 16;   // RNE
    return (u16)r;
}
__device__ __forceinline__ u32 pkbf(float a, float b) {
    return (u32)f2bf(a) | ((u32)f2bf(b) << 16);
}
__device__ __forceinline__ float bfu2f(u32 bits_lo) {     // low 16 bits -> float
    return __uint_as_float(bits_lo << 16);
}
__device__ __forceinline__ float bfu2f_hi(u32 v) {        // high 16 bits -> float
    return __uint_as_float(v & 0xffff0000u);
}

// ---------- kernel 0: repack banded W_mean blocks fp32 -> bf16 ----------
__global__ __launch_bounds__(256) void k_pack(const float* __restrict__ Wm,
                                              u16* __restrict__ ws) {
    int idx = blockIdx.x * 256 + threadIdx.x;
    if (idx >= WSP_TOTAL) return;
    int z = idx >> 18;
    int rem = idx & 262143;
    int n = rem >> 9, k = rem & 511;
    float v = Wm[(size_t)(512 * (z + 1) + n) * IN_DIM + OBS + 512 * z + k];
    ws[idx] = f2bf(v);
}

// ---------- kernel 1: banded GEMM blocks 1..10, reg-prefetch pipeline -------
#define BM 128
#define BN 128
#define BK 32
#define LDA 40                  // padded LDS rows (u16): conflict-free frags
#define LDB 40
__global__ __launch_bounds__(256) void k_gemm(const float* __restrict__ X,
                                              const float* __restrict__ Wm_raw,
                                              const u16* __restrict__ Wp,
                                              const float* __restrict__ b_mean,
                                              float* __restrict__ out_h,
                                              int packed) {
    __shared__ __attribute__((aligned(16))) u16 As[BM * LDA];
    __shared__ __attribute__((aligned(16))) u16 Bs[BN * LDB];
    int t = threadIdx.x;
    int wave = t >> 6, lane = t & 63;
    int quad = lane >> 4, r16 = lane & 15;
    int gm = blockIdx.x * BM;
    int gn = blockIdx.y * BN;
    int z = blockIdx.z;                       // band block i = z+1
    int wm = (wave >> 1) * 64;
    int wn = (wave & 1) * 64;
    int ar = t >> 1;                          // staging row 0..127
    int ah = t & 1;                           // staging 16-col half

    const float* Aptr = X + (size_t)(gm + ar) * OVERALL + z * 512 + ah * 16;
    const u16*   Bp   = Wp + (size_t)z * (512 * 512) + (size_t)(gn + ar) * 512 + ah * 16;
    const float* Br   = Wm_raw + (size_t)(512 * (z + 1) + gn + ar) * IN_DIM
                        + OBS + 512 * z + ah * 16;

    // ---- prefetch tile 0 into registers ----
    float4 a0 = *(const float4*)(Aptr);
    float4 a1 = *(const float4*)(Aptr + 4);
    float4 a2 = *(const float4*)(Aptr + 8);
    float4 a3 = *(const float4*)(Aptr + 12);
    uint4 pb0, pb1;
    float4 rb0, rb1, rb2, rb3;
    if (packed) {
        pb0 = *(const uint4*)(Bp);
        pb1 = *(const uint4*)(Bp + 8);
    } else {
        rb0 = *(const float4*)(Br);
        rb1 = *(const float4*)(Br + 4);
        rb2 = *(const float4*)(Br + 8);
        rb3 = *(const float4*)(Br + 12);
    }

    float4v acc[4][4];
#pragma unroll
    for (int i = 0; i < 4; i++)
#pragma unroll
        for (int j = 0; j < 4; j++) acc[i][j] = (float4v)0.f;

    for (int k0 = 0; k0 < 512; k0 += BK) {
        __syncthreads();                      // WAR: prior frag reads done
        // ---- commit prefetched regs to LDS (bf16) ----
        {
            uint4 w0, w1;
            w0.x = pkbf(a0.x, a0.y); w0.y = pkbf(a0.z, a0.w);
            w0.z = pkbf(a1.x, a1.y); w0.w = pkbf(a1.z, a1.w);
            w1.x = pkbf(a2.x, a2.y); w1.y = pkbf(a2.z, a2.w);
            w1.z = pkbf(a3.x, a3.y); w1.w = pkbf(a3.z, a3.w);
            *(uint4*)&As[ar * LDA + ah * 16] = w0;
            *(uint4*)&As[ar * LDA + ah * 16 + 8] = w1;
        }
        if (packed) {
            *(uint4*)&Bs[ar * LDB + ah * 16] = pb0;
            *(uint4*)&Bs[ar * LDB + ah * 16 + 8] = pb1;
        } else {
            uint4 q0, q1;
            q0.x = pkbf(rb0.x, rb0.y); q0.y = pkbf(rb0.z, rb0.w);
            q0.z = pkbf(rb1.x, rb1.y); q0.w = pkbf(rb1.z, rb1.w);
            q1.x = pkbf(rb2.x, rb2.y); q1.y = pkbf(rb2.z, rb2.w);
            q1.z = pkbf(rb3.x, rb3.y); q1.w = pkbf(rb3.z, rb3.w);
            *(uint4*)&Bs[ar * LDB + ah * 16] = q0;
            *(uint4*)&Bs[ar * LDB + ah * 16 + 8] = q1;
        }
        __syncthreads();                      // LDS visible (lgkmcnt only)

        // ---- issue next tile's global loads (stay in flight during MFMA) --
        if (k0 + BK < 512) {
            const float* ga = Aptr + k0 + BK;
            a0 = *(const float4*)(ga);
            a1 = *(const float4*)(ga + 4);
            a2 = *(const float4*)(ga + 8);
            a3 = *(const float4*)(ga + 12);
            if (packed) {
                const u16* gb = Bp + k0 + BK;
                pb0 = *(const uint4*)(gb);
                pb1 = *(const uint4*)(gb + 8);
            } else {
                const float* gb = Br + k0 + BK;
                rb0 = *(const float4*)(gb);
                rb1 = *(const float4*)(gb + 4);
                rb2 = *(const float4*)(gb + 8);
                rb3 = *(const float4*)(gb + 12);
            }
        }

        short8 af[4], bfr[4];
#pragma unroll
        for (int i = 0; i < 4; i++) {
            af[i]  = *(const short8*)&As[(wm + i * 16 + r16) * LDA + quad * 8];
            bfr[i] = *(const short8*)&Bs[(wn + i * 16 + r16) * LDB + quad * 8];
        }
#pragma unroll
        for (int i = 0; i < 4; i++)
#pragma unroll
            for (int j = 0; j < 4; j++)
                acc[i][j] = __builtin_amdgcn_mfma_f32_16x16x32_bf16(af[i], bfr[j], acc[i][j], 0, 0, 0);
    }

    // epilogue: +bias, relu, fp32 store.  C/D: col=lane&15, row=quad*4+reg
    int colblock = 512 * (z + 1);
#pragma unroll
    for (int j = 0; j < 4; j++) {
        int n_loc = gn + wn + j * 16 + r16;
        float bias = b_mean[colblock + n_loc];
#pragma unroll
        for (int i = 0; i < 4; i++) {
            int m0 = gm + wm + i * 16 + quad * 4;
#pragma unroll
            for (int r = 0; r < 4; r++) {
                float v = acc[i][j][r] + bias;
                out_h[(size_t)(m0 + r) * OVERALL + colblock + n_loc] = fmaxf(v, 0.f);
            }
        }
    }
}

// ---------- kernel 2: band block 0 (obs -> new_hidden cols 0..511) ----------
#define B0_ROWS 32
__global__ __launch_bounds__(256) void k_block0(const float* __restrict__ obs,
                                                const float* __restrict__ Wm,
                                                const float* __restrict__ b_mean,
                                                float* __restrict__ out_h) {
    __shared__ float w0[OBS * 512];           // transposed [k][n]
    __shared__ float bias_s[512];
    __shared__ float obs_s[B0_ROWS * OBS];
    int t = threadIdx.x;
    int b0 = blockIdx.x * B0_ROWS;
    for (int i = t; i < OBS * 512; i += 256) {
        int n = i / OBS, k = i - n * OBS;
        w0[k * 512 + n] = Wm[(size_t)n * IN_DIM + k];
    }
    for (int i = t; i < 512; i += 256) bias_s[i] = b_mean[i];
    for (int i = t; i < B0_ROWS * OBS; i += 256) obs_s[i] = obs[(size_t)b0 * OBS + i];
    __syncthreads();

    int n0 = (t & 127) * 4;
    int rh = t >> 7;                          // 0/1: 16-row half
#pragma unroll 4
    for (int r = 0; r < 16; r++) {
        int row = rh * 16 + r;
        float acc0 = bias_s[n0], acc1 = bias_s[n0 + 1];
        float acc2 = bias_s[n0 + 2], acc3 = bias_s[n0 + 3];
#pragma unroll
        for (int k = 0; k < OBS; k++) {
            float xo = obs_s[row * OBS + k];
            const float* wr = &w0[k * 512 + n0];
            acc0 += xo * wr[0]; acc1 += xo * wr[1];
            acc2 += xo * wr[2]; acc3 += xo * wr[3];
        }
        float4 o;
        o.x = fmaxf(acc0, 0.f); o.y = fmaxf(acc1, 0.f);
        o.z = fmaxf(acc2, 0.f); o.w = fmaxf(acc3, 0.f);
        *(float4*)&out_h[(size_t)(b0 + row) * OVERALL + n0] = o;
    }
}

// ---------- kernel 3: thin outputs via LDS-staged bf16 weights --------------
__global__ __launch_bounds__(256) void k_thin(const float* __restrict__ obs,
                                              const float* __restrict__ X,
                                              const float* __restrict__ Wm,
                                              const float* __restrict__ Wls,
                                              const float* __restrict__ b_mean,
                                              const float* __restrict__ b_logstd,
                                              float* __restrict__ out_mean,
                                              float* __restrict__ out_ls) {
    __shared__ u16 wc[2][8 * 512];            // dbuf Wls chunk, bf16
    __shared__ u16 wm11[8 * 512];             // W_mean band 11, bf16
    int t = threadIdx.x, wave = t >> 6, lane = t & 63;
    int b0 = (blockIdx.x * 4 + wave) * 4;     // 4 batch rows per wave

    // stage wm11 once + chunk 0
    for (int i = t; i < 4096; i += 256) {
        int n = i >> 9, k = i & 511;
        wm11[i] = f2bf(Wm[(size_t)(OVERALL + n) * IN_DIM + OBS + 5120 + k]);
        wc[0][i] = f2bf(Wls[(size_t)n * IN_DIM + OBS + k]);
    }

    float als[4][8], amn[4][8];
#pragma unroll
    for (int r = 0; r < 4; r++)
#pragma unroll
        for (int n = 0; n < 8; n++) { als[r][n] = 0.f; amn[r][n] = 0.f; }

    for (int c = 0; c < 11; c++) {
        int buf = c & 1;
        __syncthreads();                      // stage(c) visible; reads(c-1) done
        if (c + 1 < 11) {                     // stage next chunk
            for (int i = t; i < 4096; i += 256) {
                int n = i >> 9, k = i & 511;
                wc[buf ^ 1][i] = f2bf(Wls[(size_t)n * IN_DIM + OBS + (c + 1) * 512 + k]);
            }
        }
#pragma unroll
        for (int jj = 0; jj < 2; jj++) {
            int kloc = jj * 256 + lane * 4;
            int k = c * 512 + kloc;
            float x[4][4];
#pragma unroll
            for (int r = 0; r < 4; r++)
                *(float4*)x[r] = *(const float4*)(X + (size_t)(b0 + r) * OVERALL + k);
#pragma unroll
            for (int n = 0; n < 8; n++) {
                u32 v0 = *(const u32*)&wc[buf][n * 512 + kloc];
                u32 v1 = *(const u32*)&wc[buf][n * 512 + kloc + 2];
                float w0 = bfu2f(v0 & 0xffffu), w1 = bfu2f_hi(v0);
                float w2 = bfu2f(v1 & 0xffffu), w3 = bfu2f_hi(v1);
#pragma unroll
                for (int r = 0; r < 4; r++)
                    als[r][n] += x[r][0] * w0 + x[r][1] * w1 + x[r][2] * w2 + x[r][3] * w3;
            }
            if (c == 10) {                    // mean band: same k range
#pragma unroll
                for (int n = 0; n < 8; n++) {
                    u32 v0 = *(const u32*)&wm11[n * 512 + kloc];
                    u32 v1 = *(const u32*)&wm11[n * 512 + kloc + 2];
                    float w0 = bfu2f(v0 & 0xffffu), w1 = bfu2f_hi(v0);
                    float w2 = bfu2f(v1 & 0xffffu), w3 = bfu2f_hi(v1);
#pragma unroll
                    for (int r = 0; r < 4; r++)
                        amn[r][n] += x[r][0] * w0 + x[r][1] * w1 + x[r][2] * w2 + x[r][3] * w3;
                }
            }
        }
    }
    if (lane < OBS) {                         // obs part (fp32 exact, tiny)
#pragma unroll
        for (int r = 0; r < 4; r++) {
            float xo = obs[(size_t)(b0 + r) * OBS + lane];
#pragma unroll
            for (int n = 0; n < 8; n++)
                als[r][n] += xo * Wls[(size_t)n * IN_DIM + lane];
        }
    }
#pragma unroll
    for (int s = 1; s < 64; s <<= 1) {
#pragma unroll
        for (int r = 0; r < 4; r++)
#pragma unroll
            for (int n = 0; n < 8; n++) {
                als[r][n] += __shfl_xor(als[r][n], s, 64);
                amn[r][n] += __shfl_xor(amn[r][n], s, 64);
            }
    }
    if (lane == 0) {
#pragma unroll
        for (int r = 0; r < 4; r++)
#pragma unroll
            for (int n = 0; n < 8; n++) {
                out_ls[(size_t)(b0 + r) * ACT + n] = als[r][n] + b_logstd[n];
                out_mean[(size_t)(b0 + r) * ACT + n] = amn[r][n] + b_mean[OVERALL + n];
            }
    }
}

// ---------- kernel 4: prev_mean copy + log_std tanh (fp32 exact) ----------
__global__ __launch_bounds__(256) void k_small(const float* __restrict__ pm,
                                               const float* __restrict__ pls,
                                               float* __restrict__ o0,
                                               float* __restrict__ o1) {
    int i = blockIdx.x * 256 + threadIdx.x;     // 16384 threads x 4 floats
    float4 a = *(const float4*)(pm + (size_t)i * 4);
    *(float4*)(o0 + (size_t)i * 4) = a;
    float4 b = *(const float4*)(pls + (size_t)i * 4);
    float4 o;
    o.x = -5.f + 3.5f * (tanhf(b.x) + 1.f);
    o.y = -5.f + 3.5f * (tanhf(b.y) + 1.f);
    o.z = -5.f + 3.5f * (tanhf(b.z) + 1.f);
    o.w = -5.f + 3.5f * (tanhf(b.w) + 1.f);
    *(float4*)(o1 + (size_t)i * 4) = o;
}

extern "C" void kernel_launch(void* const* d_in, const int* in_sizes, int n_in,
                              void* d_out, int out_size, void* d_ws, size_t ws_size,
                              hipStream_t stream) {
    const float* obs         = (const float*)d_in[0];
    const float* hidden0     = (const float*)d_in[1];
    const float* prev_mean   = (const float*)d_in[2];
    const float* prev_logstd = (const float*)d_in[3];
    const float* W_mean      = (const float*)d_in[4];
    const float* b_mean      = (const float*)d_in[5];
    const float* W_logstd    = (const float*)d_in[6];
    const float* b_logstd    = (const float*)d_in[7];

    float* out   = (float*)d_out;
    float* o_pm  = out + O_PM;
    float* o_ls  = out + O_LS;
    float* o_nh  = out + O_NH;
    float* o_nm  = out + O_NM;
    float* o_nls = out + O_NLS;
    u16*   ws    = (u16*)d_ws;

    int packed = (ws != nullptr && ws_size >= WSP_BYTES) ? 1 : 0;

    if (packed) {
        k_pack<<<(WSP_TOTAL + 255) / 256, 256, 0, stream>>>(W_mean, ws);
    }
    k_gemm<<<dim3(BATCH / BM, 512 / BN, NL), 256, 0, stream>>>(
        hidden0, W_mean, ws, b_mean, o_nh, packed);
    k_block0<<<BATCH / B0_ROWS, 256, 0, stream>>>(obs, W_mean, b_mean, o_nh);
    k_thin<<<BATCH / 16, 256, 0, stream>>>(obs, hidden0, W_mean, W_logstd,
                                           b_mean, b_logstd, o_nm, o_nls);
    k_small<<<64, 256, 0, stream>>>(prev_mean, prev_logstd, o_pm, o_ls);
}

// Round 4
// 452.267 us; speedup vs baseline: 1.1855x; 1.1855x over previous
//
#include <hip/hip_runtime.h>
#include <math.h>

typedef unsigned short u16;
typedef unsigned int u32;
typedef __attribute__((ext_vector_type(8))) short short8;   // 8 bf16 = 4 VGPRs
typedef __attribute__((ext_vector_type(4))) float float4v;  // MFMA accum

// ---------- constants ----------
#define BATCH   8192
#define OBS     21
#define HID     512
#define NL      10
#define OVERALL 5632            // HID*(NL+1)
#define IN_DIM  5653            // OBS + OVERALL
#define ACT     8

// output element offsets (flat concat, fp32 elements)
#define O_PM   0
#define O_LS   65536
#define O_NH   131072
#define O_NM   (131072 + BATCH*OVERALL)     // 46268416
#define O_NLS  (O_NM + 65536)               // 46333952

// packed workspace: 10 x 512 x 512 bf16 weight blocks (K-contiguous)
#define WSP_TOTAL (10*512*512)
#define WSP_BYTES ((size_t)WSP_TOTAL * 2)

__device__ __forceinline__ u16 f2bf(float f) {
    u32 u = __float_as_uint(f);
    u32 r = (u + 0x7fffu + ((u >> 16) & 1u)) >> 16;   // RNE
    return (u16)r;
}
__device__ __forceinline__ u32 pkbf(float a, float b) {
    return (u32)f2bf(a) | ((u32)f2bf(b) << 16);
}
__device__ __forceinline__ void gload_lds16(const void* g, void* l) {
    __builtin_amdgcn_global_load_lds(
        (const __attribute__((address_space(1))) char*)g,
        (__attribute__((address_space(3))) char*)l, 16, 0, 0);
}

// ---------- kernel 0: repack banded W_mean blocks fp32 -> bf16 ----------
__global__ __launch_bounds__(256) void k_pack(const float* __restrict__ Wm,
                                              u16* __restrict__ ws) {
    int idx = blockIdx.x * 256 + threadIdx.x;
    if (idx >= WSP_TOTAL) return;
    int z = idx >> 18;
    int rem = idx & 262143;
    int n = rem >> 9, k = rem & 511;
    float v = Wm[(size_t)(512 * (z + 1) + n) * IN_DIM + OBS + 512 * z + k];
    ws[idx] = f2bf(v);
}

// ---------- kernel 1: fused slice kernel -----------------------------------
// grid (64, 11): block = 128 batch rows (gm) x one 512-col X slice (z).
//  z<10 : GEMM band z+1 (BN=512, out cols 512(z+1)..512(z+2)) + logstd partial
//  z==10: logstd partial + new_mean (band 11)
#define BM 128
#define BK 32
#define LDA 40                  // padded bf16 LDS rows for A
__global__ __launch_bounds__(1024, 4) void k_fused(
        const float* __restrict__ X,
        const float* __restrict__ Wm_raw,
        const u16* __restrict__ Wp,
        const float* __restrict__ Wls_raw,
        const float* __restrict__ b_mean,
        float* __restrict__ out_h,
        float* __restrict__ out_ls,
        float* __restrict__ out_mean,
        int packed) {
    __shared__ __attribute__((aligned(16))) u16 As[BM * LDA];      // 10.0 KB
    __shared__ __attribute__((aligned(16))) u16 Bs[512 * 32];      // 32 KB, xor-swizzled
    __shared__ __attribute__((aligned(16))) u16 Wt[16 * 520];      // 16.25 KB logstd slice
    u16* Wt2 = (u16*)Bs;                     // z==10 only: mean slice aliases Bs

    int t = threadIdx.x;
    int w = t >> 6, lane = t & 63;
    int quad = lane >> 4, r16 = lane & 15;
    int gm = blockIdx.x * BM;
    int z = blockIdx.y;
    bool mainz = (z < 10);
    int wm = (w >> 3) * 64;                  // GEMM wave tile: 2 m-pos x 8 n-pos
    int wn = (w & 7) * 64;

    // ---- stage logstd slice (bf16) + (z==10) mean slice ----
    {
        int n = t >> 7;                      // 0..7
        int k4 = (t & 127) * 4;
        const float* wr = Wls_raw + (size_t)n * IN_DIM + OBS + z * 512 + k4;
        u16* dst = &Wt[n * 520 + k4];
        dst[0] = f2bf(wr[0]); dst[1] = f2bf(wr[1]);
        dst[2] = f2bf(wr[2]); dst[3] = f2bf(wr[3]);
        if (!mainz) {
            const float* wr2 = Wm_raw + (size_t)(OVERALL + n) * IN_DIM + OBS + z * 512 + k4;
            u16* d2 = &Wt2[n * 520 + k4];
            d2[0] = f2bf(wr2[0]); d2[1] = f2bf(wr2[1]);
            d2[2] = f2bf(wr2[2]); d2[3] = f2bf(wr2[3]);
        }
    }

    // ---- A prefetch pointer: 1 float4 per thread per chunk ----
    int arow = t >> 3;                       // 0..127
    int acol = (t & 7) * 4;                  // 0..28
    const float* gA = X + (size_t)(gm + arow) * OVERALL + (size_t)z * 512 + acol;
    float4 areg = *(const float4*)(gA);      // chunk 0

    float4v acc[4][4];
#pragma unroll
    for (int i = 0; i < 4; i++)
#pragma unroll
        for (int j = 0; j < 4; j++) acc[i][j] = (float4v)0.f;
    float4v accL = (float4v)0.f;             // logstd (w<8) or mean (z==10, w>=8)

    for (int it = 0; it < 16; ++it) {
        int k0 = it * BK;
        __syncthreads();                     // prev frag reads done; LDS reusable
        // ---- A: cvt prefetched regs -> bf16 LDS ----
        {
            uint2 p;
            p.x = pkbf(areg.x, areg.y);
            p.y = pkbf(areg.z, areg.w);
            *(uint2*)&As[arow * LDA + acol] = p;
        }
        // ---- B: global -> LDS, xor-swizzled slots ----
        if (mainz) {
            if (packed) {
#pragma unroll
                for (int i2 = 0; i2 < 2; ++i2) {
                    int base_row = i2 * 256 + w * 16;
                    int row = base_row + (lane >> 2);
                    int slot = lane & 3;
                    int j = (slot - row) & 3;    // logical k-chunk in this slot
                    const u16* g = Wp + (size_t)z * 262144 + (size_t)row * 512 + k0 + j * 8;
                    gload_lds16(g, (char*)Bs + base_row * 64);
                }
            } else {
#pragma unroll
                for (int i2 = 0; i2 < 2; ++i2) {
                    int row = i2 * 256 + w * 16 + (lane >> 2);
                    int slot = lane & 3;
                    int j = (slot - row) & 3;
                    const float* g = Wm_raw + (size_t)(512 * (z + 1) + row) * IN_DIM
                                     + OBS + (size_t)z * 512 + k0 + j * 8;
                    uint4 q;
                    q.x = pkbf(g[0], g[1]); q.y = pkbf(g[2], g[3]);
                    q.z = pkbf(g[4], g[5]); q.w = pkbf(g[6], g[7]);
                    *(uint4*)&Bs[row * 32 + slot * 8] = q;
                }
            }
        }
        __syncthreads();                     // tile visible (drains B loads)
        if (it < 15) areg = *(const float4*)(gA + (it + 1) * BK);  // covered by MFMA

        if (mainz) {
            short8 bfr[4];
#pragma unroll
            for (int j = 0; j < 4; j++) {
                int n = wn + j * 16 + r16;
                int s = (quad + n) & 3;
                bfr[j] = *(const short8*)&Bs[n * 32 + s * 8];
            }
#pragma unroll
            for (int i2 = 0; i2 < 4; i2++) {
                short8 af = *(const short8*)&As[(wm + i2 * 16 + r16) * LDA + quad * 8];
#pragma unroll
                for (int j = 0; j < 4; j++)
                    acc[i2][j] = __builtin_amdgcn_mfma_f32_16x16x32_bf16(af, bfr[j], acc[i2][j], 0, 0, 0);
            }
        }
        if (w < 8) {                         // logstd partial: rows w*16..w*16+16
            short8 aL = *(const short8*)&As[(w * 16 + r16) * LDA + quad * 8];
            short8 bL = *(const short8*)&Wt[r16 * 520 + k0 + quad * 8];
            accL = __builtin_amdgcn_mfma_f32_16x16x32_bf16(aL, bL, accL, 0, 0, 0);
        } else if (!mainz) {                 // mean band: rows (w-8)*16..
            short8 aL = *(const short8*)&As[((w - 8) * 16 + r16) * LDA + quad * 8];
            short8 bL = *(const short8*)&Wt2[r16 * 520 + k0 + quad * 8];
            accL = __builtin_amdgcn_mfma_f32_16x16x32_bf16(aL, bL, accL, 0, 0, 0);
        }
    }

    // ---- epilogues.  C/D layout: col = lane&15, row = quad*4 + reg ----
    if (mainz) {
        int colblock = (z + 1) * 512;
#pragma unroll
        for (int j = 0; j < 4; j++) {
            int n_loc = wn + j * 16 + r16;
            float bias = b_mean[colblock + n_loc];
#pragma unroll
            for (int i2 = 0; i2 < 4; i2++) {
                int m0 = gm + wm + i2 * 16 + quad * 4;
#pragma unroll
                for (int r = 0; r < 4; r++) {
                    float v = acc[i2][j][r] + bias;
                    out_h[(size_t)(m0 + r) * OVERALL + colblock + n_loc] = fmaxf(v, 0.f);
                }
            }
        }
    }
    if (w < 8) {                             // logstd partial -> atomic
        if (r16 < ACT) {
#pragma unroll
            for (int r = 0; r < 4; r++) {
                int row = gm + w * 16 + quad * 4 + r;
                atomicAdd(&out_ls[(size_t)row * ACT + r16], accL[r]);
            }
        }
    } else if (!mainz) {                     // mean: exact, direct store
        if (r16 < ACT) {
            float bias = b_mean[OVERALL + r16];
#pragma unroll
            for (int r = 0; r < 4; r++) {
                int row = gm + (w - 8) * 16 + quad * 4 + r;
                out_mean[(size_t)row * ACT + r16] = accL[r] + bias;
            }
        }
    }
}

// ---------- kernel 2: band block 0 (obs -> new_hidden cols 0..511) ----------
#define B0_ROWS 32
__global__ __launch_bounds__(256) void k_block0(const float* __restrict__ obs,
                                                const float* __restrict__ Wm,
                                                const float* __restrict__ b_mean,
                                                float* __restrict__ out_h) {
    __shared__ float w0[OBS * 512];           // transposed [k][n]
    __shared__ float bias_s[512];
    __shared__ float obs_s[B0_ROWS * OBS];
    int t = threadIdx.x;
    int b0 = blockIdx.x * B0_ROWS;
    for (int i = t; i < OBS * 512; i += 256) {
        int n = i / OBS, k = i - n * OBS;
        w0[k * 512 + n] = Wm[(size_t)n * IN_DIM + k];
    }
    for (int i = t; i < 512; i += 256) bias_s[i] = b_mean[i];
    for (int i = t; i < B0_ROWS * OBS; i += 256) obs_s[i] = obs[(size_t)b0 * OBS + i];
    __syncthreads();

    int n0 = (t & 127) * 4;
    int rh = t >> 7;
#pragma unroll 4
    for (int r = 0; r < 16; r++) {
        int row = rh * 16 + r;
        float acc0 = bias_s[n0], acc1 = bias_s[n0 + 1];
        float acc2 = bias_s[n0 + 2], acc3 = bias_s[n0 + 3];
#pragma unroll
        for (int k = 0; k < OBS; k++) {
            float xo = obs_s[row * OBS + k];
            const float* wr = &w0[k * 512 + n0];
            acc0 += xo * wr[0]; acc1 += xo * wr[1];
            acc2 += xo * wr[2]; acc3 += xo * wr[3];
        }
        float4 o;
        o.x = fmaxf(acc0, 0.f); o.y = fmaxf(acc1, 0.f);
        o.z = fmaxf(acc2, 0.f); o.w = fmaxf(acc3, 0.f);
        *(float4*)&out_h[(size_t)(b0 + row) * OVERALL + n0] = o;
    }
}

// ---------- kernel 3: finisher: logstd obs-part + bias, tanh, copy ----------
__global__ __launch_bounds__(256) void k_finish(const float* __restrict__ obs,
                                                const float* __restrict__ Wls,
                                                const float* __restrict__ b_logstd,
                                                const float* __restrict__ pm,
                                                const float* __restrict__ pls,
                                                float* __restrict__ o_pm,
                                                float* __restrict__ o_lstd,
                                                float* __restrict__ o_nls) {
    __shared__ float wobs[ACT * OBS];
    __shared__ float bls[ACT];
    int t = threadIdx.x;
    if (t < ACT * OBS) wobs[t] = Wls[(size_t)(t / OBS) * IN_DIM + (t % OBS)];
    if (t < ACT) bls[t] = b_logstd[t];
    __syncthreads();
    int row = blockIdx.x * 256 + t;           // 8192 rows
    float ob[OBS];
#pragma unroll
    for (int k = 0; k < OBS; k++) ob[k] = obs[(size_t)row * OBS + k];
#pragma unroll
    for (int n = 0; n < ACT; n++) {
        float a = bls[n];
#pragma unroll
        for (int k = 0; k < OBS; k++) a += ob[k] * wobs[n * OBS + k];
        o_nls[(size_t)row * ACT + n] += a;    // completes the atomic partials
    }
    // prev_mean copy + log_std tanh transform
    float4 p0 = *(const float4*)(pm + (size_t)row * ACT);
    float4 p1 = *(const float4*)(pm + (size_t)row * ACT + 4);
    *(float4*)(o_pm + (size_t)row * ACT) = p0;
    *(float4*)(o_pm + (size_t)row * ACT + 4) = p1;
    float4 l0 = *(const float4*)(pls + (size_t)row * ACT);
    float4 l1 = *(const float4*)(pls + (size_t)row * ACT + 4);
    float4 q0, q1;
    q0.x = -5.f + 3.5f * (tanhf(l0.x) + 1.f);
    q0.y = -5.f + 3.5f * (tanhf(l0.y) + 1.f);
    q0.z = -5.f + 3.5f * (tanhf(l0.z) + 1.f);
    q0.w = -5.f + 3.5f * (tanhf(l0.w) + 1.f);
    q1.x = -5.f + 3.5f * (tanhf(l1.x) + 1.f);
    q1.y = -5.f + 3.5f * (tanhf(l1.y) + 1.f);
    q1.z = -5.f + 3.5f * (tanhf(l1.z) + 1.f);
    q1.w = -5.f + 3.5f * (tanhf(l1.w) + 1.f);
    *(float4*)(o_lstd + (size_t)row * ACT) = q0;
    *(float4*)(o_lstd + (size_t)row * ACT + 4) = q1;
}

extern "C" void kernel_launch(void* const* d_in, const int* in_sizes, int n_in,
                              void* d_out, int out_size, void* d_ws, size_t ws_size,
                              hipStream_t stream) {
    const float* obs         = (const float*)d_in[0];
    const float* hidden0     = (const float*)d_in[1];
    const float* prev_mean   = (const float*)d_in[2];
    const float* prev_logstd = (const float*)d_in[3];
    const float* W_mean      = (const float*)d_in[4];
    const float* b_mean      = (const float*)d_in[5];
    const float* W_logstd    = (const float*)d_in[6];
    const float* b_logstd    = (const float*)d_in[7];

    float* out   = (float*)d_out;
    float* o_pm  = out + O_PM;
    float* o_ls  = out + O_LS;
    float* o_nh  = out + O_NH;
    float* o_nm  = out + O_NM;
    float* o_nls = out + O_NLS;
    u16*   ws    = (u16*)d_ws;

    int packed = (ws != nullptr && ws_size >= WSP_BYTES) ? 1 : 0;

    if (packed) {
        k_pack<<<(WSP_TOTAL + 255) / 256, 256, 0, stream>>>(W_mean, ws);
    }
    hipMemsetAsync(o_nls, 0, (size_t)BATCH * ACT * sizeof(float), stream);
    k_fused<<<dim3(BATCH / BM, NL + 1), 1024, 0, stream>>>(
        hidden0, W_mean, ws, W_logstd, b_mean, o_nh, o_nls, o_nm, packed);
    k_block0<<<BATCH / B0_ROWS, 256, 0, stream>>>(obs, W_mean, b_mean, o_nh);
    k_finish<<<BATCH / 256, 256, 0, stream>>>(obs, W_logstd, b_logstd,
                                              prev_mean, prev_logstd,
                                              o_pm, o_ls, o_nls);
}